// Round 1
// baseline (882.728 us; speedup 1.0000x reference)
//
#include <hip/hip_runtime.h>
#include <hip/hip_bf16.h>

#define NB 32
#define NN 784
#define DIMC 512
#define NH 8
#define KD 32
#define VD 128
#define QKV_OUT 1536
#define VAL_ATTN 1024
#define SROW 808  // padded LDS row (808 % 32 == 8 -> rows land on different banks)

typedef __attribute__((ext_vector_type(4))) float floatx4;
typedef __attribute__((ext_vector_type(8))) short shortx8;
typedef __attribute__((ext_vector_type(4))) unsigned short ushortx4;
typedef __attribute__((ext_vector_type(4))) unsigned int uintx4;
typedef unsigned short ushort_t;

__device__ __forceinline__ unsigned short f2bf(float f) {
    union { float f; unsigned int u; } v; v.f = f;
    unsigned int r = v.u + 0x7fffu + ((v.u >> 16) & 1u);
    return (unsigned short)(r >> 16);
}

// ---------------- BN prep: scale = g*rsqrt(v+eps), shift = b - m*scale ----------
__global__ void bn_prep(const float* __restrict__ g, const float* __restrict__ b,
                        const float* __restrict__ m, const float* __restrict__ v,
                        float* __restrict__ scale, float* __restrict__ shift, int n) {
    int i = blockIdx.x * 256 + threadIdx.x;
    if (i < n) {
        float s = g[i] * rsqrtf(v[i] + 1e-5f);
        scale[i] = s;
        shift[i] = b[i] - m[i] * s;
    }
}

// ---------------- QKV GEMM + BN + scatter to q/k/v(transposed) ------------------
// out[m][o] = BN(sum_c x[m][c] * w[o][c]);  m = b*784+n, o = h*192 + {q:0..31, k:32..63, v:64..191}
__global__ __launch_bounds__(256, 2)
void qkv_gemm(const float* __restrict__ x, const float* __restrict__ w,
              const float* __restrict__ scale, const float* __restrict__ shift,
              ushort_t* __restrict__ qbuf, ushort_t* __restrict__ kbuf,
              ushort_t* __restrict__ vbuf) {
    __shared__ ushort_t As[128 * 32];
    __shared__ ushort_t Bs[128 * 32];
    const int t = threadIdx.x;
    const int m0 = blockIdx.x * 128;
    const int n0 = blockIdx.y * 128;
    const int wave = t >> 6, lane = t & 63;
    const int wm = wave >> 1, wn = wave & 1;
    const int l16 = lane & 15, quad = lane >> 4;
    const int row = t >> 1, half = t & 1;

    floatx4 acc[4][4] = {};

    const float* srcA = x + (size_t)(m0 + row) * DIMC + half * 16;
    const float* srcB = w + (size_t)(n0 + row) * DIMC + half * 16;
    ushort_t* dstA = As + row * 32 + half * 16;
    ushort_t* dstB = Bs + row * 32 + half * 16;

    for (int k0 = 0; k0 < DIMC; k0 += 32) {
        #pragma unroll
        for (int i = 0; i < 4; ++i) {
            floatx4 fa = *(const floatx4*)(srcA + k0 + i * 4);
            floatx4 fb = *(const floatx4*)(srcB + k0 + i * 4);
            ushortx4 ua, ub;
            #pragma unroll
            for (int jj = 0; jj < 4; ++jj) { ua[jj] = f2bf(fa[jj]); ub[jj] = f2bf(fb[jj]); }
            *(ushortx4*)(dstA + i * 4) = ua;
            *(ushortx4*)(dstB + i * 4) = ub;
        }
        __syncthreads();
        shortx8 af[4], bfr[4];
        #pragma unroll
        for (int i = 0; i < 4; ++i)
            af[i] = *(const shortx8*)(As + (wm * 64 + i * 16 + l16) * 32 + quad * 8);
        #pragma unroll
        for (int j = 0; j < 4; ++j)
            bfr[j] = *(const shortx8*)(Bs + (wn * 64 + j * 16 + l16) * 32 + quad * 8);
        #pragma unroll
        for (int i = 0; i < 4; ++i)
            #pragma unroll
            for (int j = 0; j < 4; ++j)
                acc[i][j] = __builtin_amdgcn_mfma_f32_16x16x32_bf16(af[i], bfr[j], acc[i][j], 0, 0, 0);
        __syncthreads();
    }

    // epilogue: BN then scatter to q/k/v buffers (bf16)
    #pragma unroll
    for (int j = 0; j < 4; ++j) {
        const int gn = n0 + wn * 64 + j * 16 + l16;
        const float sc = scale[gn], sh = shift[gn];
        const int h = gn / 192, rr = gn % 192;
        #pragma unroll
        for (int i = 0; i < 4; ++i) {
            #pragma unroll
            for (int r = 0; r < 4; ++r) {
                const int gm = m0 + wm * 64 + i * 16 + quad * 4 + r;
                const int bb = gm / NN, n = gm - bb * NN;
                const float val = acc[i][j][r] * sc + sh;
                const ushort_t bv = f2bf(val);
                const size_t bh = (size_t)bb * NH + h;
                if (rr < KD)             qbuf[(bh * NN + n) * KD + rr] = bv;
                else if (rr < 2 * KD)    kbuf[(bh * NN + n) * KD + (rr - KD)] = bv;
                else                     vbuf[(bh * VD + (rr - 2 * KD)) * NN + n] = bv;  // transposed [d][n]
            }
        }
    }
}

// ---------------- Attention: one block per (b,h,16-row q-tile) ------------------
__global__ __launch_bounds__(256, 2)
void attn_kernel(const ushort_t* __restrict__ qbuf, const ushort_t* __restrict__ kbuf,
                 const ushort_t* __restrict__ vbuf, const float* __restrict__ ab,
                 const int* __restrict__ idxs, ushort_t* __restrict__ obuf) {
    __shared__ float S[16 * SROW];
    const int t = threadIdx.x;
    const int wave = t >> 6, lane = t & 63;
    const int l16 = lane & 15, quad = lane >> 4;
    const int bid = blockIdx.x;
    const int qt = bid % 49;
    const int bh = bid / 49;
    const int h = bh & 7;
    const int i0 = qt * 16;

    const ushort_t* qbase = qbuf + ((size_t)bh * NN + i0) * KD;
    const ushort_t* kbase = kbuf + (size_t)bh * NN * KD;
    const float* abrow = ab + h * NN;
    const float scale = 0.17677669529663687f;  // 1/sqrt(32)

    // q fragment: A[m=lane&15][k=quad*8+j], K=32 covered by one frag
    shortx8 qf = *(const shortx8*)(qbase + l16 * KD + quad * 8);

    // S phase: 49 j-tiles split across 4 waves
    for (int jt = wave; jt < 49; jt += 4) {
        shortx8 kf = *(const shortx8*)(kbase + (jt * 16 + l16) * KD + quad * 8);
        floatx4 d = {};
        d = __builtin_amdgcn_mfma_f32_16x16x32_bf16(qf, kf, d, 0, 0, 0);
        const int j = jt * 16 + l16;
        #pragma unroll
        for (int r = 0; r < 4; ++r) {
            const int i = quad * 4 + r;
            const int idx = idxs[(i0 + i) * NN + j];
            S[i * SROW + j] = d[r] * scale + abrow[idx];
        }
    }
    // zero-pad cols 784..799 (read by PV's last m-tile)
    {
        const int r = t >> 4, c = NN + (t & 15);
        S[r * SROW + c] = 0.0f;
    }
    __syncthreads();

    // softmax: 16 threads per row
    {
        const int r = t >> 4, c0 = t & 15;
        float* Srow = S + r * SROW;
        float mx = -3.0e38f;
        for (int j = c0; j < NN; j += 16) mx = fmaxf(mx, Srow[j]);
        #pragma unroll
        for (int off = 8; off >= 1; off >>= 1) mx = fmaxf(mx, __shfl_xor(mx, off, 16));
        float sum = 0.0f;
        for (int j = c0; j < NN; j += 16) {
            float e = __expf(Srow[j] - mx);
            Srow[j] = e;
            sum += e;
        }
        #pragma unroll
        for (int off = 8; off >= 1; off >>= 1) sum += __shfl_xor(sum, off, 16);
        const float inv = 1.0f / sum;
        for (int j = c0; j < NN; j += 16) Srow[j] *= inv;
    }
    __syncthreads();

    // PV: O(16x128) = P(16x800) @ V(800x128), wave w -> vd tiles {2w, 2w+1}
    floatx4 oacc[2] = {};
    const ushort_t* vbase = vbuf + (size_t)bh * VD * NN;
    for (int mt = 0; mt < 25; ++mt) {
        const int m0 = mt * 32 + quad * 8;
        const float* ps = S + l16 * SROW + m0;
        floatx4 p0 = *(const floatx4*)(ps);
        floatx4 p1 = *(const floatx4*)(ps + 4);
        shortx8 af;
        #pragma unroll
        for (int jj = 0; jj < 4; ++jj) { af[jj] = (short)f2bf(p0[jj]); af[jj + 4] = (short)f2bf(p1[jj]); }
        #pragma unroll
        for (int vt = 0; vt < 2; ++vt) {
            const int vd = (wave * 2 + vt) * 16 + l16;
            shortx8 bfv = {};
            if (m0 < NN) bfv = *(const shortx8*)(vbase + (size_t)vd * NN + m0);
            oacc[vt] = __builtin_amdgcn_mfma_f32_16x16x32_bf16(af, bfv, oacc[vt], 0, 0, 0);
        }
    }

    // epilogue: hardswish, store bf16 o
    const int b = bh >> 3;
    #pragma unroll
    for (int vt = 0; vt < 2; ++vt) {
        const int vd = (wave * 2 + vt) * 16 + l16;
        #pragma unroll
        for (int r = 0; r < 4; ++r) {
            const int i = i0 + quad * 4 + r;
            const float o = oacc[vt][r];
            const float hs = o * fminf(fmaxf(o + 3.0f, 0.0f), 6.0f) * (1.0f / 6.0f);
            obuf[((size_t)b * NN + i) * VAL_ATTN + h * VD + vd] = f2bf(hs);
        }
    }
}

// ---------------- Proj GEMM + BN -> fp32 out ------------------------------------
__global__ __launch_bounds__(256, 2)
void proj_gemm(const ushort_t* __restrict__ obuf, const float* __restrict__ pw,
               const float* __restrict__ pscale, const float* __restrict__ pshift,
               float* __restrict__ out) {
    __shared__ ushort_t As[128 * 32];
    __shared__ ushort_t Bs[128 * 32];
    const int t = threadIdx.x;
    const int m0 = blockIdx.x * 128;
    const int n0 = blockIdx.y * 128;
    const int wave = t >> 6, lane = t & 63;
    const int wm = wave >> 1, wn = wave & 1;
    const int l16 = lane & 15, quad = lane >> 4;
    const int row = t >> 1, half = t & 1;

    floatx4 acc[4][4] = {};

    const ushort_t* srcA = obuf + (size_t)(m0 + row) * VAL_ATTN + half * 16;
    const float*    srcB = pw + (size_t)(n0 + row) * VAL_ATTN + half * 16;
    ushort_t* dstA = As + row * 32 + half * 16;
    ushort_t* dstB = Bs + row * 32 + half * 16;

    for (int k0 = 0; k0 < VAL_ATTN; k0 += 32) {
        *(uintx4*)(dstA)     = *(const uintx4*)(srcA + k0);
        *(uintx4*)(dstA + 8) = *(const uintx4*)(srcA + k0 + 8);
        #pragma unroll
        for (int i = 0; i < 4; ++i) {
            floatx4 fb = *(const floatx4*)(srcB + k0 + i * 4);
            ushortx4 ub;
            #pragma unroll
            for (int jj = 0; jj < 4; ++jj) ub[jj] = f2bf(fb[jj]);
            *(ushortx4*)(dstB + i * 4) = ub;
        }
        __syncthreads();
        shortx8 af[4], bfr[4];
        #pragma unroll
        for (int i = 0; i < 4; ++i)
            af[i] = *(const shortx8*)(As + (wm * 64 + i * 16 + l16) * 32 + quad * 8);
        #pragma unroll
        for (int j = 0; j < 4; ++j)
            bfr[j] = *(const shortx8*)(Bs + (wn * 64 + j * 16 + l16) * 32 + quad * 8);
        #pragma unroll
        for (int i = 0; i < 4; ++i)
            #pragma unroll
            for (int j = 0; j < 4; ++j)
                acc[i][j] = __builtin_amdgcn_mfma_f32_16x16x32_bf16(af[i], bfr[j], acc[i][j], 0, 0, 0);
        __syncthreads();
    }

    #pragma unroll
    for (int j = 0; j < 4; ++j) {
        const int gn = n0 + wn * 64 + j * 16 + l16;
        const float sc = pscale[gn], sh = pshift[gn];
        #pragma unroll
        for (int i = 0; i < 4; ++i) {
            #pragma unroll
            for (int r = 0; r < 4; ++r) {
                const int gm = m0 + wm * 64 + i * 16 + quad * 4 + r;
                out[(size_t)gm * DIMC + gn] = acc[i][j][r] * sc + sh;
            }
        }
    }
}

extern "C" void kernel_launch(void* const* d_in, const int* in_sizes, int n_in,
                              void* d_out, int out_size, void* d_ws, size_t ws_size,
                              hipStream_t stream) {
    const float* x      = (const float*)d_in[0];
    const float* qkv_w  = (const float*)d_in[1];
    const float* qkv_g  = (const float*)d_in[2];
    const float* qkv_b  = (const float*)d_in[3];
    const float* qkv_m  = (const float*)d_in[4];
    const float* qkv_v  = (const float*)d_in[5];
    const float* ab     = (const float*)d_in[6];
    const float* proj_w = (const float*)d_in[7];
    const float* proj_g = (const float*)d_in[8];
    const float* proj_b = (const float*)d_in[9];
    const float* proj_m = (const float*)d_in[10];
    const float* proj_v = (const float*)d_in[11];
    const int*   idxs   = (const int*)d_in[12];
    float* out = (float*)d_out;

    char* ws = (char*)d_ws;
    size_t off = 0;
    auto alloc = [&](size_t bytes) {
        void* p = ws + off;
        off = (off + bytes + 255) & ~(size_t)255;
        return p;
    };
    ushort_t* qbuf = (ushort_t*)alloc((size_t)NB * NH * NN * KD * 2);
    ushort_t* kbuf = (ushort_t*)alloc((size_t)NB * NH * NN * KD * 2);
    ushort_t* vbuf = (ushort_t*)alloc((size_t)NB * NH * VD * NN * 2);
    ushort_t* obuf = (ushort_t*)alloc((size_t)NB * NN * VAL_ATTN * 2);
    float* qscale = (float*)alloc(QKV_OUT * 4);
    float* qshift = (float*)alloc(QKV_OUT * 4);
    float* pscale = (float*)alloc(DIMC * 4);
    float* pshift = (float*)alloc(DIMC * 4);

    bn_prep<<<6, 256, 0, stream>>>(qkv_g, qkv_b, qkv_m, qkv_v, qscale, qshift, QKV_OUT);
    bn_prep<<<2, 256, 0, stream>>>(proj_g, proj_b, proj_m, proj_v, pscale, pshift, DIMC);
    qkv_gemm<<<dim3(196, 12), 256, 0, stream>>>(x, qkv_w, qscale, qshift, qbuf, kbuf, vbuf);
    attn_kernel<<<dim3(NB * NH * 49), 256, 0, stream>>>(qbuf, kbuf, vbuf, ab, idxs, obuf);
    proj_gemm<<<dim3(196, 4), 256, 0, stream>>>(obuf, proj_w, pscale, pshift, out);
}

// Round 2
// 507.829 us; speedup vs baseline: 1.7382x; 1.7382x over previous
//
#include <hip/hip_runtime.h>
#include <hip/hip_bf16.h>

#define NB 32
#define NN 784
#define NNP 896        // N padded to 7*128 k-chunks
#define DIMC 512
#define NH 8
#define KD 32
#define VD 128
#define QKV_OUT 1536
#define VAL_ATTN 1024
#define PROW 136       // P LDS row stride (ushorts): (l16*68 + quad*4)%32 spreads 8 banks/group
#define KROW 40        // K LDS row stride (ushorts): (row*20 + q4*4)%32 spreads fully

typedef __attribute__((ext_vector_type(4))) float floatx4;
typedef __attribute__((ext_vector_type(8))) short shortx8;
typedef __attribute__((ext_vector_type(4))) unsigned short ushortx4;
typedef __attribute__((ext_vector_type(4))) unsigned int uintx4;
typedef unsigned short ushort_t;

__device__ __forceinline__ unsigned short f2bf(float f) {
    union { float f; unsigned int u; } v; v.f = f;
    unsigned int r = v.u + 0x7fffu + ((v.u >> 16) & 1u);
    return (unsigned short)(r >> 16);
}
__device__ __forceinline__ float bf2f(unsigned short s) {
    union { unsigned int u; float f; } v; v.u = ((unsigned int)s) << 16;
    return v.f;
}

// ---------------- BN prep ----------------
__global__ void bn_prep(const float* __restrict__ g, const float* __restrict__ b,
                        const float* __restrict__ m, const float* __restrict__ v,
                        float* __restrict__ scale, float* __restrict__ shift, int n) {
    int i = blockIdx.x * 256 + threadIdx.x;
    if (i < n) {
        float s = g[i] * rsqrtf(v[i] + 1e-5f);
        scale[i] = s;
        shift[i] = b[i] - m[i] * s;
    }
}

// ---------------- bias table: bias[h][i][j] = ab[h][idxs[i*784+j]], padded j -> -30000
__global__ void bias_prep(const float* __restrict__ ab, const int* __restrict__ idxs,
                          ushort_t* __restrict__ bias) {
    int tid = blockIdx.x * 256 + threadIdx.x;
    if (tid >= NH * NN * NNP) return;
    int j = tid % NNP;
    int rest = tid / NNP;
    int i = rest % NN;
    int h = rest / NN;
    float v = -30000.0f;
    if (j < NN) v = ab[h * NN + idxs[i * NN + j]];
    bias[tid] = f2bf(v);
}

// ---------------- QKV GEMM + BN + scatter ----------------
__global__ __launch_bounds__(256, 2)
void qkv_gemm(const float* __restrict__ x, const float* __restrict__ w,
              const float* __restrict__ scale, const float* __restrict__ shift,
              ushort_t* __restrict__ qbuf, ushort_t* __restrict__ kbuf,
              ushort_t* __restrict__ vbuf) {
    __shared__ ushort_t As[128 * 32];
    __shared__ ushort_t Bs[128 * 32];
    const int t = threadIdx.x;
    const int m0 = blockIdx.x * 128;
    const int n0 = blockIdx.y * 128;
    const int wave = t >> 6, lane = t & 63;
    const int wm = wave >> 1, wn = wave & 1;
    const int l16 = lane & 15, quad = lane >> 4;
    const int row = t >> 1, half = t & 1;

    floatx4 acc[4][4] = {};

    const float* srcA = x + (size_t)(m0 + row) * DIMC + half * 16;
    const float* srcB = w + (size_t)(n0 + row) * DIMC + half * 16;
    ushort_t* dstA = As + row * 32 + half * 16;
    ushort_t* dstB = Bs + row * 32 + half * 16;

    for (int k0 = 0; k0 < DIMC; k0 += 32) {
        #pragma unroll
        for (int i = 0; i < 4; ++i) {
            floatx4 fa = *(const floatx4*)(srcA + k0 + i * 4);
            floatx4 fb = *(const floatx4*)(srcB + k0 + i * 4);
            ushortx4 ua, ub;
            #pragma unroll
            for (int jj = 0; jj < 4; ++jj) { ua[jj] = f2bf(fa[jj]); ub[jj] = f2bf(fb[jj]); }
            *(ushortx4*)(dstA + i * 4) = ua;
            *(ushortx4*)(dstB + i * 4) = ub;
        }
        __syncthreads();
        shortx8 af[4], bfr[4];
        #pragma unroll
        for (int i = 0; i < 4; ++i)
            af[i] = *(const shortx8*)(As + (wm * 64 + i * 16 + l16) * 32 + quad * 8);
        #pragma unroll
        for (int j = 0; j < 4; ++j)
            bfr[j] = *(const shortx8*)(Bs + (wn * 64 + j * 16 + l16) * 32 + quad * 8);
        #pragma unroll
        for (int i = 0; i < 4; ++i)
            #pragma unroll
            for (int j = 0; j < 4; ++j)
                acc[i][j] = __builtin_amdgcn_mfma_f32_16x16x32_bf16(af[i], bfr[j], acc[i][j], 0, 0, 0);
        __syncthreads();
    }

    #pragma unroll
    for (int j = 0; j < 4; ++j) {
        const int gn = n0 + wn * 64 + j * 16 + l16;
        const float sc = scale[gn], sh = shift[gn];
        const int h = gn / 192, rr = gn % 192;
        #pragma unroll
        for (int i = 0; i < 4; ++i) {
            #pragma unroll
            for (int r = 0; r < 4; ++r) {
                const int gm = m0 + wm * 64 + i * 16 + quad * 4 + r;
                const int bb = gm / NN, n = gm - bb * NN;
                const float val = acc[i][j][r] * sc + sh;
                const ushort_t bv = f2bf(val);
                const size_t bh = (size_t)bb * NH + h;
                if (rr < KD)             qbuf[(bh * NN + n) * KD + rr] = bv;
                else if (rr < 2 * KD)    kbuf[(bh * NNP + n) * KD + (rr - KD)] = bv;
                else                     vbuf[(bh * VD + (rr - 2 * KD)) * NNP + n] = bv;
            }
        }
    }
}

// ---------------- Attention: block = (b,h,64-row q-tile), single-pass no-max softmax
__global__ __launch_bounds__(256, 4)
void attn_kernel(const ushort_t* __restrict__ qbuf, const ushort_t* __restrict__ kbuf,
                 const ushort_t* __restrict__ vbuf, const ushort_t* __restrict__ bias,
                 ushort_t* __restrict__ obuf) {
    __shared__ ushort_t Ks[128 * KROW];
    __shared__ ushort_t Ps[64 * PROW];
    __shared__ float linv[64];

    const int t = threadIdx.x;
    const int wave = t >> 6, lane = t & 63;
    const int l16 = lane & 15, quad = lane >> 4;
    const int bid = blockIdx.x;
    const int b = bid & 31;
    const int hq = bid >> 5;
    const int h = hq & 7;
    const int qt = hq >> 3;            // 0..12
    const int bh = b * NH + h;
    const int i0 = qt * 64;
    const int mvalid = min(4, (NN - i0 + 15) >> 4);   // 4, except last tile -> 1
    const bool swave = wave < mvalid;
    const float scale = 0.17677669529663687f;

    const ushort_t* qbase = qbuf + ((size_t)bh * NN + i0) * KD;
    const ushort_t* kbase = kbuf + (size_t)bh * NNP * KD;
    const ushort_t* vbase = vbuf + (size_t)bh * VD * NNP;
    const ushort_t* bbase = bias + ((size_t)h * NN + i0) * NNP;

    shortx8 qf = {};
    if (swave) qf = *(const shortx8*)(qbase + (wave * 16 + l16) * KD + quad * 8);

    float lacc[4] = {0.f, 0.f, 0.f, 0.f};
    floatx4 oacc[4][2] = {};

    const int srow = t >> 2, sq4 = t & 3;   // K staging: 4 threads/row, 16B each

    for (int c = 0; c < 7; ++c) {
        // ---- stage K chunk (128 x 32 bf16) ----
        #pragma unroll
        for (int rr = 0; rr < 2; ++rr) {
            const int row = rr * 64 + srow;
            *(uintx4*)(Ks + row * KROW + sq4 * 8) =
                *(const uintx4*)(kbase + (size_t)(c * 128 + row) * KD + sq4 * 8);
        }
        __syncthreads();

        // ---- S phase: wave w -> its 16 q-rows ----
        if (swave) {
            #pragma unroll
            for (int jt = 0; jt < 8; ++jt) {
                shortx8 kf = *(const shortx8*)(Ks + (jt * 16 + l16) * KROW + quad * 8);
                floatx4 d = {};
                d = __builtin_amdgcn_mfma_f32_16x16x32_bf16(qf, kf, d, 0, 0, 0);
                const int j = c * 128 + jt * 16 + l16;
                #pragma unroll
                for (int r = 0; r < 4; ++r) {
                    const int lr = wave * 16 + quad * 4 + r;
                    const float bv = bf2f(bbase[(size_t)lr * NNP + j]);
                    const float e = __expf(d[r] * scale + bv);
                    lacc[r] += e;
                    Ps[lr * PROW + jt * 16 + l16] = f2bf(e);
                }
            }
        }
        __syncthreads();

        // ---- PV phase: wave w -> vd cols [32w, 32w+32) for all m ----
        {
            const ushort_t* vb = vbase + (size_t)(wave * 32) * NNP + c * 128;
            #pragma unroll
            for (int ks = 0; ks < 4; ++ks) {
                shortx8 v0 = *(const shortx8*)(vb + (size_t)l16 * NNP + ks * 32 + quad * 8);
                shortx8 v1 = *(const shortx8*)(vb + (size_t)(16 + l16) * NNP + ks * 32 + quad * 8);
                #pragma unroll
                for (int ms = 0; ms < 4; ++ms) {
                    if (ms < mvalid) {
                        shortx8 af = *(const shortx8*)(Ps + (ms * 16 + l16) * PROW + ks * 32 + quad * 8);
                        oacc[ms][0] = __builtin_amdgcn_mfma_f32_16x16x32_bf16(af, v0, oacc[ms][0], 0, 0, 0);
                        oacc[ms][1] = __builtin_amdgcn_mfma_f32_16x16x32_bf16(af, v1, oacc[ms][1], 0, 0, 0);
                    }
                }
            }
        }
    }

    // ---- row-sum reduce, 1/l ----
    if (swave) {
        #pragma unroll
        for (int r = 0; r < 4; ++r) {
            float s = lacc[r];
            s += __shfl_xor(s, 1, 16);
            s += __shfl_xor(s, 2, 16);
            s += __shfl_xor(s, 4, 16);
            s += __shfl_xor(s, 8, 16);
            if (l16 == r) linv[wave * 16 + quad * 4 + r] = 1.0f / s;
        }
    }
    __syncthreads();

    // ---- epilogue: normalize, hardswish, store ----
    #pragma unroll
    for (int ms = 0; ms < 4; ++ms) {
        if (ms < mvalid) {
            #pragma unroll
            for (int vt = 0; vt < 2; ++vt) {
                const int vd = h * VD + wave * 32 + vt * 16 + l16;
                #pragma unroll
                for (int r = 0; r < 4; ++r) {
                    const int row = i0 + ms * 16 + quad * 4 + r;
                    const float o = oacc[ms][vt][r] * linv[ms * 16 + quad * 4 + r];
                    const float hs = o * fminf(fmaxf(o + 3.0f, 0.0f), 6.0f) * (1.0f / 6.0f);
                    obuf[((size_t)b * NN + row) * VAL_ATTN + vd] = f2bf(hs);
                }
            }
        }
    }
}

// ---------------- Proj GEMM + BN -> fp32 out ----------------
__global__ __launch_bounds__(256, 2)
void proj_gemm(const ushort_t* __restrict__ obuf, const float* __restrict__ pw,
               const float* __restrict__ pscale, const float* __restrict__ pshift,
               float* __restrict__ out) {
    __shared__ ushort_t As[128 * 32];
    __shared__ ushort_t Bs[128 * 32];
    const int t = threadIdx.x;
    const int m0 = blockIdx.x * 128;
    const int n0 = blockIdx.y * 128;
    const int wave = t >> 6, lane = t & 63;
    const int wm = wave >> 1, wn = wave & 1;
    const int l16 = lane & 15, quad = lane >> 4;
    const int row = t >> 1, half = t & 1;

    floatx4 acc[4][4] = {};

    const ushort_t* srcA = obuf + (size_t)(m0 + row) * VAL_ATTN + half * 16;
    const float*    srcB = pw + (size_t)(n0 + row) * VAL_ATTN + half * 16;
    ushort_t* dstA = As + row * 32 + half * 16;
    ushort_t* dstB = Bs + row * 32 + half * 16;

    for (int k0 = 0; k0 < VAL_ATTN; k0 += 32) {
        *(uintx4*)(dstA)     = *(const uintx4*)(srcA + k0);
        *(uintx4*)(dstA + 8) = *(const uintx4*)(srcA + k0 + 8);
        #pragma unroll
        for (int i = 0; i < 4; ++i) {
            floatx4 fb = *(const floatx4*)(srcB + k0 + i * 4);
            ushortx4 ub;
            #pragma unroll
            for (int jj = 0; jj < 4; ++jj) ub[jj] = f2bf(fb[jj]);
            *(ushortx4*)(dstB + i * 4) = ub;
        }
        __syncthreads();
        shortx8 af[4], bfr[4];
        #pragma unroll
        for (int i = 0; i < 4; ++i)
            af[i] = *(const shortx8*)(As + (wm * 64 + i * 16 + l16) * 32 + quad * 8);
        #pragma unroll
        for (int j = 0; j < 4; ++j)
            bfr[j] = *(const shortx8*)(Bs + (wn * 64 + j * 16 + l16) * 32 + quad * 8);
        #pragma unroll
        for (int i = 0; i < 4; ++i)
            #pragma unroll
            for (int j = 0; j < 4; ++j)
                acc[i][j] = __builtin_amdgcn_mfma_f32_16x16x32_bf16(af[i], bfr[j], acc[i][j], 0, 0, 0);
        __syncthreads();
    }

    #pragma unroll
    for (int j = 0; j < 4; ++j) {
        const int gn = n0 + wn * 64 + j * 16 + l16;
        const float sc = pscale[gn], sh = pshift[gn];
        #pragma unroll
        for (int i = 0; i < 4; ++i) {
            #pragma unroll
            for (int r = 0; r < 4; ++r) {
                const int gm = m0 + wm * 64 + i * 16 + quad * 4 + r;
                out[(size_t)gm * DIMC + gn] = acc[i][j][r] * sc + sh;
            }
        }
    }
}

extern "C" void kernel_launch(void* const* d_in, const int* in_sizes, int n_in,
                              void* d_out, int out_size, void* d_ws, size_t ws_size,
                              hipStream_t stream) {
    const float* x      = (const float*)d_in[0];
    const float* qkv_w  = (const float*)d_in[1];
    const float* qkv_g  = (const float*)d_in[2];
    const float* qkv_b  = (const float*)d_in[3];
    const float* qkv_m  = (const float*)d_in[4];
    const float* qkv_v  = (const float*)d_in[5];
    const float* ab     = (const float*)d_in[6];
    const float* proj_w = (const float*)d_in[7];
    const float* proj_g = (const float*)d_in[8];
    const float* proj_b = (const float*)d_in[9];
    const float* proj_m = (const float*)d_in[10];
    const float* proj_v = (const float*)d_in[11];
    const int*   idxs   = (const int*)d_in[12];
    float* out = (float*)d_out;

    char* ws = (char*)d_ws;
    size_t off = 0;
    auto alloc = [&](size_t bytes) {
        void* p = ws + off;
        off = (off + bytes + 255) & ~(size_t)255;
        return p;
    };
    ushort_t* qbuf = (ushort_t*)alloc((size_t)NB * NH * NN * KD * 2);
    ushort_t* kbuf = (ushort_t*)alloc((size_t)NB * NH * NNP * KD * 2);
    ushort_t* vbuf = (ushort_t*)alloc((size_t)NB * NH * VD * NNP * 2);
    ushort_t* obuf = (ushort_t*)alloc((size_t)NB * NN * VAL_ATTN * 2);
    ushort_t* bias = (ushort_t*)alloc((size_t)NH * NN * NNP * 2);
    float* qscale = (float*)alloc(QKV_OUT * 4);
    float* qshift = (float*)alloc(QKV_OUT * 4);
    float* pscale = (float*)alloc(DIMC * 4);
    float* pshift = (float*)alloc(DIMC * 4);

    bn_prep<<<6, 256, 0, stream>>>(qkv_g, qkv_b, qkv_m, qkv_v, qscale, qshift, QKV_OUT);
    bn_prep<<<2, 256, 0, stream>>>(proj_g, proj_b, proj_m, proj_v, pscale, pshift, DIMC);
    bias_prep<<<(NH * NN * NNP + 255) / 256, 256, 0, stream>>>(ab, idxs, bias);
    qkv_gemm<<<dim3(196, 12), 256, 0, stream>>>(x, qkv_w, qscale, qshift, qbuf, kbuf, vbuf);
    attn_kernel<<<dim3(32 * NH * 13), 256, 0, stream>>>(qbuf, kbuf, vbuf, bias, obuf);
    proj_gemm<<<dim3(196, 4), 256, 0, stream>>>(obuf, proj_w, pscale, pshift, out);
}

// Round 3
// 406.203 us; speedup vs baseline: 2.1731x; 1.2502x over previous
//
#include <hip/hip_runtime.h>
#include <hip/hip_bf16.h>

#define NB 32
#define NN 784
#define NNP 896        // N padded to 7*128 k-chunks
#define DIMC 512
#define NH 8
#define KD 32
#define VD 128
#define QKV_OUT 1536
#define VAL_ATTN 1024
#define PROW 136       // P LDS row stride (ushorts)
#define KROW 40        // K LDS row stride (ushorts)

typedef __attribute__((ext_vector_type(4))) float floatx4;
typedef __attribute__((ext_vector_type(8))) short shortx8;
typedef __attribute__((ext_vector_type(4))) unsigned short ushortx4;
typedef __attribute__((ext_vector_type(4))) unsigned int uintx4;
typedef unsigned short ushort_t;

__device__ __forceinline__ unsigned short f2bf(float f) {
    union { float f; unsigned int u; } v; v.f = f;
    unsigned int r = v.u + 0x7fffu + ((v.u >> 16) & 1u);
    return (unsigned short)(r >> 16);
}
__device__ __forceinline__ float bf2f(unsigned short s) {
    union { unsigned int u; float f; } v; v.u = ((unsigned int)s) << 16;
    return v.f;
}
__device__ __forceinline__ void gld16(void* lds, const void* g) {
    __builtin_amdgcn_global_load_lds((const __attribute__((address_space(1))) void*)g,
                                     (__attribute__((address_space(3))) void*)lds, 16, 0, 0);
}

// ---------------- fp32 -> bf16 bulk convert (x4 vectorized) ----------------
__global__ void cvt_bf16(const float* __restrict__ in, ushort_t* __restrict__ out, int n4) {
    int i = blockIdx.x * 256 + threadIdx.x;
    if (i < n4) {
        floatx4 f = ((const floatx4*)in)[i];
        ushortx4 u;
        #pragma unroll
        for (int j = 0; j < 4; ++j) u[j] = f2bf(f[j]);
        ((ushortx4*)out)[i] = u;
    }
}

// ---------------- BN prep ----------------
__global__ void bn_prep(const float* __restrict__ g, const float* __restrict__ b,
                        const float* __restrict__ m, const float* __restrict__ v,
                        float* __restrict__ scale, float* __restrict__ shift, int n) {
    int i = blockIdx.x * 256 + threadIdx.x;
    if (i < n) {
        float s = g[i] * rsqrtf(v[i] + 1e-5f);
        scale[i] = s;
        shift[i] = b[i] - m[i] * s;
    }
}

// ---------------- bias table: bias[h][i][j] = ab[h][idxs[i*784+j]], padded j -> -30000
__global__ void bias_prep(const float* __restrict__ ab, const int* __restrict__ idxs,
                          ushort_t* __restrict__ bias) {
    int tid = blockIdx.x * 256 + threadIdx.x;
    if (tid >= NH * NN * NNP) return;
    int j = tid % NNP;
    int rest = tid / NNP;
    int i = rest % NN;
    int h = rest / NN;
    float v = -30000.0f;
    if (j < NN) v = ab[h * NN + idxs[i * NN + j]];
    bias[tid] = f2bf(v);
}

// ---------------- QKV GEMM (bf16 in, global_load_lds staging) + BN + scatter ----
__global__ __launch_bounds__(256, 2)
void qkv_gemm(const ushort_t* __restrict__ xb, const ushort_t* __restrict__ wb,
              const float* __restrict__ scale, const float* __restrict__ shift,
              ushort_t* __restrict__ qbuf, ushort_t* __restrict__ kbuf,
              ushort_t* __restrict__ vbuf) {
    __shared__ ushort_t As[128 * 32];
    __shared__ ushort_t Bs[128 * 32];
    const int t = threadIdx.x;
    const int m0 = blockIdx.x * 128;
    const int n0 = blockIdx.y * 128;
    const int wave = t >> 6, lane = t & 63;
    const int wm = wave >> 1, wn = wave & 1;
    const int l16 = lane & 15, quad = lane >> 4;
    const int r4 = lane >> 2, c8 = lane & 3;

    floatx4 acc[4][4] = {};

    const ushort_t* agp = xb + (size_t)(m0 + wave * 16 + r4) * DIMC + c8 * 8;
    const ushort_t* bgp = wb + (size_t)(n0 + wave * 16 + r4) * DIMC + c8 * 8;
    ushort_t* alp = As + wave * 16 * 32;   // wave-uniform; HW adds lane*16B
    ushort_t* blp = Bs + wave * 16 * 32;

    for (int k0 = 0; k0 < DIMC; k0 += 32) {
        gld16(alp,           agp + k0);
        gld16(alp + 64 * 32, agp + (size_t)64 * DIMC + k0);
        gld16(blp,           bgp + k0);
        gld16(blp + 64 * 32, bgp + (size_t)64 * DIMC + k0);
        __syncthreads();
        shortx8 af[4], bfr[4];
        #pragma unroll
        for (int i = 0; i < 4; ++i)
            af[i] = *(const shortx8*)(As + (wm * 64 + i * 16 + l16) * 32 + quad * 8);
        #pragma unroll
        for (int j = 0; j < 4; ++j)
            bfr[j] = *(const shortx8*)(Bs + (wn * 64 + j * 16 + l16) * 32 + quad * 8);
        #pragma unroll
        for (int i = 0; i < 4; ++i)
            #pragma unroll
            for (int j = 0; j < 4; ++j)
                acc[i][j] = __builtin_amdgcn_mfma_f32_16x16x32_bf16(af[i], bfr[j], acc[i][j], 0, 0, 0);
        __syncthreads();
    }

    // epilogue: BN + scatter. Section (q/k/v) is wave-uniform per j.
    #pragma unroll
    for (int j = 0; j < 4; ++j) {
        const int gn = n0 + wn * 64 + j * 16 + l16;
        const float sc = scale[gn], sh = shift[gn];
        const int h = gn / 192, rr = gn % 192;
        if (rr < 2 * KD) {
            #pragma unroll
            for (int i = 0; i < 4; ++i) {
                #pragma unroll
                for (int r = 0; r < 4; ++r) {
                    const int gm = m0 + wm * 64 + i * 16 + quad * 4 + r;
                    const int bb = gm / NN, n = gm - bb * NN;
                    const ushort_t bv = f2bf(acc[i][j][r] * sc + sh);
                    const size_t bh = (size_t)bb * NH + h;
                    if (rr < KD) qbuf[(bh * NN + n) * KD + rr] = bv;
                    else         kbuf[(bh * NNP + n) * KD + (rr - KD)] = bv;
                }
            }
        } else {
            const int d = rr - 2 * KD;
            #pragma unroll
            for (int i = 0; i < 4; ++i) {
                const int gm0 = m0 + wm * 64 + i * 16 + quad * 4;
                const int bb = gm0 / NN, n = gm0 - bb * NN;
                const size_t bh = (size_t)bb * NH + h;
                ushortx4 pk;
                #pragma unroll
                for (int r = 0; r < 4; ++r) pk[r] = f2bf(acc[i][j][r] * sc + sh);
                *(ushortx4*)(vbuf + (bh * VD + d) * NNP + n) = pk;
            }
        }
    }
}

// ---------------- Attention: block = (b,h,64-row q-tile), single-pass no-max softmax
__global__ __launch_bounds__(256, 4)
void attn_kernel(const ushort_t* __restrict__ qbuf, const ushort_t* __restrict__ kbuf,
                 const ushort_t* __restrict__ vbuf, const ushort_t* __restrict__ bias,
                 ushort_t* __restrict__ obuf) {
    __shared__ ushort_t Ks[128 * KROW];
    __shared__ ushort_t Ps[64 * PROW];
    __shared__ float linv[64];

    const int t = threadIdx.x;
    const int wave = t >> 6, lane = t & 63;
    const int l16 = lane & 15, quad = lane >> 4;
    const int bid = blockIdx.x;
    const int b = bid & 31;
    const int hq = bid >> 5;
    const int h = hq & 7;
    const int qt = hq >> 3;            // 0..12
    const int bh = b * NH + h;
    const int i0 = qt * 64;
    const int mvalid = min(4, (NN - i0 + 15) >> 4);
    const bool swave = wave < mvalid;
    const float scale = 0.17677669529663687f;

    const ushort_t* qbase = qbuf + ((size_t)bh * NN + i0) * KD;
    const ushort_t* kbase = kbuf + (size_t)bh * NNP * KD;
    const ushort_t* vbase = vbuf + (size_t)bh * VD * NNP;
    const ushort_t* bbase = bias + ((size_t)h * NN + i0) * NNP;

    shortx8 qf = {};
    if (swave) qf = *(const shortx8*)(qbase + (wave * 16 + l16) * KD + quad * 8);

    float lacc[4] = {0.f, 0.f, 0.f, 0.f};
    floatx4 oacc[4][2] = {};

    const int srow = t >> 2, sq4 = t & 3;

    for (int c = 0; c < 7; ++c) {
        #pragma unroll
        for (int rr = 0; rr < 2; ++rr) {
            const int row = rr * 64 + srow;
            *(uintx4*)(Ks + row * KROW + sq4 * 8) =
                *(const uintx4*)(kbase + (size_t)(c * 128 + row) * KD + sq4 * 8);
        }
        __syncthreads();

        if (swave) {
            #pragma unroll
            for (int jt = 0; jt < 8; ++jt) {
                shortx8 kf = *(const shortx8*)(Ks + (jt * 16 + l16) * KROW + quad * 8);
                floatx4 d = {};
                d = __builtin_amdgcn_mfma_f32_16x16x32_bf16(qf, kf, d, 0, 0, 0);
                const int j = c * 128 + jt * 16 + l16;
                #pragma unroll
                for (int r = 0; r < 4; ++r) {
                    const int lr = wave * 16 + quad * 4 + r;
                    const float bv = bf2f(bbase[(size_t)lr * NNP + j]);
                    const float e = __expf(d[r] * scale + bv);
                    lacc[r] += e;
                    Ps[lr * PROW + jt * 16 + l16] = f2bf(e);
                }
            }
        }
        __syncthreads();

        {
            const ushort_t* vb = vbase + (size_t)(wave * 32) * NNP + c * 128;
            #pragma unroll
            for (int ks = 0; ks < 4; ++ks) {
                shortx8 v0 = *(const shortx8*)(vb + (size_t)l16 * NNP + ks * 32 + quad * 8);
                shortx8 v1 = *(const shortx8*)(vb + (size_t)(16 + l16) * NNP + ks * 32 + quad * 8);
                #pragma unroll
                for (int ms = 0; ms < 4; ++ms) {
                    if (ms < mvalid) {
                        shortx8 af = *(const shortx8*)(Ps + (ms * 16 + l16) * PROW + ks * 32 + quad * 8);
                        oacc[ms][0] = __builtin_amdgcn_mfma_f32_16x16x32_bf16(af, v0, oacc[ms][0], 0, 0, 0);
                        oacc[ms][1] = __builtin_amdgcn_mfma_f32_16x16x32_bf16(af, v1, oacc[ms][1], 0, 0, 0);
                    }
                }
            }
        }
    }

    if (swave) {
        #pragma unroll
        for (int r = 0; r < 4; ++r) {
            float s = lacc[r];
            s += __shfl_xor(s, 1, 16);
            s += __shfl_xor(s, 2, 16);
            s += __shfl_xor(s, 4, 16);
            s += __shfl_xor(s, 8, 16);
            if (l16 == r) linv[wave * 16 + quad * 4 + r] = 1.0f / s;
        }
    }
    __syncthreads();

    #pragma unroll
    for (int ms = 0; ms < 4; ++ms) {
        if (ms < mvalid) {
            #pragma unroll
            for (int vt = 0; vt < 2; ++vt) {
                const int vd = h * VD + wave * 32 + vt * 16 + l16;
                #pragma unroll
                for (int r = 0; r < 4; ++r) {
                    const int row = i0 + ms * 16 + quad * 4 + r;
                    const float o = oacc[ms][vt][r] * linv[ms * 16 + quad * 4 + r];
                    const float hs = o * fminf(fmaxf(o + 3.0f, 0.0f), 6.0f) * (1.0f / 6.0f);
                    obuf[((size_t)b * NN + row) * VAL_ATTN + vd] = f2bf(hs);
                }
            }
        }
    }
}

// ---------------- Proj GEMM (bf16 in, global_load_lds staging) + BN -> fp32 ------
__global__ __launch_bounds__(256, 2)
void proj_gemm(const ushort_t* __restrict__ obuf, const ushort_t* __restrict__ pwb,
               const float* __restrict__ pscale, const float* __restrict__ pshift,
               float* __restrict__ out) {
    __shared__ ushort_t As[128 * 32];
    __shared__ ushort_t Bs[128 * 32];
    const int t = threadIdx.x;
    const int m0 = blockIdx.x * 128;
    const int n0 = blockIdx.y * 128;
    const int wave = t >> 6, lane = t & 63;
    const int wm = wave >> 1, wn = wave & 1;
    const int l16 = lane & 15, quad = lane >> 4;
    const int r4 = lane >> 2, c8 = lane & 3;

    floatx4 acc[4][4] = {};

    const ushort_t* agp = obuf + (size_t)(m0 + wave * 16 + r4) * VAL_ATTN + c8 * 8;
    const ushort_t* bgp = pwb + (size_t)(n0 + wave * 16 + r4) * VAL_ATTN + c8 * 8;
    ushort_t* alp = As + wave * 16 * 32;
    ushort_t* blp = Bs + wave * 16 * 32;

    for (int k0 = 0; k0 < VAL_ATTN; k0 += 32) {
        gld16(alp,           agp + k0);
        gld16(alp + 64 * 32, agp + (size_t)64 * VAL_ATTN + k0);
        gld16(blp,           bgp + k0);
        gld16(blp + 64 * 32, bgp + (size_t)64 * VAL_ATTN + k0);
        __syncthreads();
        shortx8 af[4], bfr[4];
        #pragma unroll
        for (int i = 0; i < 4; ++i)
            af[i] = *(const shortx8*)(As + (wm * 64 + i * 16 + l16) * 32 + quad * 8);
        #pragma unroll
        for (int j = 0; j < 4; ++j)
            bfr[j] = *(const shortx8*)(Bs + (wn * 64 + j * 16 + l16) * 32 + quad * 8);
        #pragma unroll
        for (int i = 0; i < 4; ++i)
            #pragma unroll
            for (int j = 0; j < 4; ++j)
                acc[i][j] = __builtin_amdgcn_mfma_f32_16x16x32_bf16(af[i], bfr[j], acc[i][j], 0, 0, 0);
        __syncthreads();
    }

    #pragma unroll
    for (int j = 0; j < 4; ++j) {
        const int gn = n0 + wn * 64 + j * 16 + l16;
        const float sc = pscale[gn], sh = pshift[gn];
        #pragma unroll
        for (int i = 0; i < 4; ++i) {
            #pragma unroll
            for (int r = 0; r < 4; ++r) {
                const int gm = m0 + wm * 64 + i * 16 + quad * 4 + r;
                out[(size_t)gm * DIMC + gn] = acc[i][j][r] * sc + sh;
            }
        }
    }
}

extern "C" void kernel_launch(void* const* d_in, const int* in_sizes, int n_in,
                              void* d_out, int out_size, void* d_ws, size_t ws_size,
                              hipStream_t stream) {
    const float* x      = (const float*)d_in[0];
    const float* qkv_w  = (const float*)d_in[1];
    const float* qkv_g  = (const float*)d_in[2];
    const float* qkv_b  = (const float*)d_in[3];
    const float* qkv_m  = (const float*)d_in[4];
    const float* qkv_v  = (const float*)d_in[5];
    const float* ab     = (const float*)d_in[6];
    const float* proj_w = (const float*)d_in[7];
    const float* proj_g = (const float*)d_in[8];
    const float* proj_b = (const float*)d_in[9];
    const float* proj_m = (const float*)d_in[10];
    const float* proj_v = (const float*)d_in[11];
    const int*   idxs   = (const int*)d_in[12];
    float* out = (float*)d_out;

    char* ws = (char*)d_ws;
    size_t off = 0;
    auto alloc = [&](size_t bytes) {
        void* p = ws + off;
        off = (off + bytes + 255) & ~(size_t)255;
        return p;
    };
    ushort_t* qbuf = (ushort_t*)alloc((size_t)NB * NH * NN * KD * 2);
    ushort_t* kbuf = (ushort_t*)alloc((size_t)NB * NH * NNP * KD * 2);
    ushort_t* vbuf = (ushort_t*)alloc((size_t)NB * NH * VD * NNP * 2);
    ushort_t* obuf = (ushort_t*)alloc((size_t)NB * NN * VAL_ATTN * 2);
    ushort_t* bias = (ushort_t*)alloc((size_t)NH * NN * NNP * 2);
    ushort_t* xb   = (ushort_t*)alloc((size_t)NB * NN * DIMC * 2);
    ushort_t* wqb  = (ushort_t*)alloc((size_t)QKV_OUT * DIMC * 2);
    ushort_t* pwb  = (ushort_t*)alloc((size_t)DIMC * VAL_ATTN * 2);
    float* qscale = (float*)alloc(QKV_OUT * 4);
    float* qshift = (float*)alloc(QKV_OUT * 4);
    float* pscale = (float*)alloc(DIMC * 4);
    float* pshift = (float*)alloc(DIMC * 4);

    const int nx4 = NB * NN * DIMC / 4;
    const int nw4 = QKV_OUT * DIMC / 4;
    const int np4 = DIMC * VAL_ATTN / 4;
    cvt_bf16<<<(nx4 + 255) / 256, 256, 0, stream>>>(x, xb, nx4);
    cvt_bf16<<<(nw4 + 255) / 256, 256, 0, stream>>>(qkv_w, wqb, nw4);
    cvt_bf16<<<(np4 + 255) / 256, 256, 0, stream>>>(proj_w, pwb, np4);
    bn_prep<<<6, 256, 0, stream>>>(qkv_g, qkv_b, qkv_m, qkv_v, qscale, qshift, QKV_OUT);
    bn_prep<<<2, 256, 0, stream>>>(proj_g, proj_b, proj_m, proj_v, pscale, pshift, DIMC);
    bias_prep<<<(NH * NN * NNP + 255) / 256, 256, 0, stream>>>(ab, idxs, bias);
    qkv_gemm<<<dim3(196, 12), 256, 0, stream>>>(xb, wqb, qscale, qshift, qbuf, kbuf, vbuf);
    attn_kernel<<<dim3(32 * NH * 13), 256, 0, stream>>>(qbuf, kbuf, vbuf, bias, obuf);
    proj_gemm<<<dim3(196, 4), 256, 0, stream>>>(obuf, pwb, pscale, pshift, out);
}